// Round 7
// baseline (97.552 us; speedup 1.0000x reference)
//
#include <hip/hip_runtime.h>

// STAttn v6: B,T,N,D=32,32,64,512; H=64; OUT=256.
// Kernel A (512 blocks x 512 thr = 8 waves = 2 bt x (nh,jh)):
//   Phase 1: h = x @ ue_w^T via mfma_f32_32x32x16_bf16, fragments loaded
//            DIRECTLY from global (no LDS, no barriers in k-loop) — latency
//            hidden by 128 independent 16B loads/thread + 16 waves/CU.
//            bf16 hi/lo trunc-split (3 MFMAs) for fp32-grade accuracy.
//   Phase 2: e = lrelu(h+bias)@w_w (w_b dropped: softmax shift-invariant).
//   Phase 3: softmax over N=64; pooling attr = sum_n a_n x_n (x L2/L3-warm).
// MODE 0 (ws ok, confirmed R6): attr -> d_ws; kernel B (fc2) does the fc GEMM.
// MODE 1 fallback: fc fused in-block.

typedef __attribute__((ext_vector_type(8)))  short bf16x8;
typedef __attribute__((ext_vector_type(16))) float f32x16;

// fp32 -> bf16 hi (trunc) + lo (residual, trunc); alo*blo (~2^-16) dropped.
__device__ __forceinline__ void split8t(const float* __restrict__ v,
                                        bf16x8& h8, bf16x8& l8) {
#pragma unroll
    for (int i = 0; i < 8; ++i) {
        const unsigned u = __float_as_uint(v[i]);
        h8[i] = (short)(u >> 16);
        const float hf = __uint_as_float(u & 0xFFFF0000u);
        l8[i] = (short)(__float_as_uint(v[i] - hf) >> 16);
    }
}

template<int MODE>
__global__ __launch_bounds__(512, 4) void stattn_main(
    const float* __restrict__ inp,    // [1024][64][512]
    const float* __restrict__ ue_w,   // [64][512]
    const float* __restrict__ ue_b,   // [64]
    const float* __restrict__ be,     // [64]
    const float* __restrict__ w_w,    // [64]
    const float* __restrict__ fc1_w,  // [256][512] (MODE 1 only)
    const float* __restrict__ fc1_b,  // [256]      (MODE 1 only)
    float* __restrict__ dst)          // MODE 0: attr[1024][512]; MODE 1: out
{
    __shared__ float ep_s[2][2][64];  // [g][jh][n]
    __shared__ float a_s[2][64];
    __shared__ __align__(16) float attr_s[2][512];  // MODE 1 only

    const int tid = threadIdx.x;
    const int wv  = tid >> 6;
    const int l   = tid & 63;
    const int l31 = l & 31;
    const int hi5 = l >> 5;
    const int g   = wv >> 2;         // bt within block
    const int nh  = (wv >> 1) & 1;   // token half
    const int jh  = wv & 1;          // hidden half
    const int kq  = hi5 * 8;         // k sub-offset within 16-wide step

    const long bt = (long)blockIdx.x * 2 + g;
    const float* __restrict__ xg = inp + bt * (64 * 512);

    // ---- Phase 1: 32x32 h-tile per wave, K=512, straight from global ----
    const float* __restrict__ arow = xg   + (nh * 32 + l31) * 512 + kq;
    const float* __restrict__ brow = ue_w + (jh * 32 + l31) * 512 + kq;

    f32x16 acc = {};
#pragma unroll 4
    for (int ks = 0; ks < 32; ++ks) {
        const int k = ks * 16;
        float av[8], bv[8];
        *reinterpret_cast<float4*>(&av[0]) = *reinterpret_cast<const float4*>(&arow[k]);
        *reinterpret_cast<float4*>(&av[4]) = *reinterpret_cast<const float4*>(&arow[k + 4]);
        *reinterpret_cast<float4*>(&bv[0]) = *reinterpret_cast<const float4*>(&brow[k]);
        *reinterpret_cast<float4*>(&bv[4]) = *reinterpret_cast<const float4*>(&brow[k + 4]);
        bf16x8 ah, al, bh, bl;
        split8t(av, ah, al);
        split8t(bv, bh, bl);
        acc = __builtin_amdgcn_mfma_f32_32x32x16_bf16(ah, bh, acc, 0, 0, 0);
        acc = __builtin_amdgcn_mfma_f32_32x32x16_bf16(al, bh, acc, 0, 0, 0);
        acc = __builtin_amdgcn_mfma_f32_32x32x16_bf16(ah, bl, acc, 0, 0, 0);
    }

    // ---- Phase 2: bias + lrelu + dot w_w -> partial e in LDS ----
    // C/D layout (m74/m101): col j = l&31, row n = (r&3) + 8*(r>>2) + 4*(l>>5)
    {
        const int j = jh * 32 + l31;
        const float bias = ue_b[j] + be[j];
        const float ww   = w_w[j];
        float ep[16];
#pragma unroll
        for (int r = 0; r < 16; ++r) {
            float hv = acc[r] + bias;
            hv = hv > 0.f ? hv : 0.2f * hv;
            float p = hv * ww;
            p += __shfl_xor(p, 1);
            p += __shfl_xor(p, 2);
            p += __shfl_xor(p, 4);
            p += __shfl_xor(p, 8);
            p += __shfl_xor(p, 16);
            ep[r] = p;
        }
        if (l31 == 0) {
#pragma unroll
            for (int r = 0; r < 16; ++r) {
                const int nr = (r & 3) + 8 * (r >> 2) + 4 * hi5;
                ep_s[g][jh][nh * 32 + nr] = ep[r];
            }
        }
    }
    __syncthreads();

    // ---- softmax over 64 tokens (per g; all 4 waves compute, one writes) ----
    {
        float v  = ep_s[g][0][l] + ep_s[g][1][l];
        float mx = v;
#pragma unroll
        for (int off = 32; off >= 1; off >>= 1) mx = fmaxf(mx, __shfl_xor(mx, off));
        const float ex = expf(v - mx);
        float sm = ex;
#pragma unroll
        for (int off = 32; off >= 1; off >>= 1) sm += __shfl_xor(sm, off);
        if ((wv & 3) == 0) a_s[g][l] = ex / sm;
    }
    __syncthreads();

    // ---- Phase 3: pooling; threads 0-255 -> g=0, 256-511 -> g=1; float2/thread
    {
        const int gg = tid >> 8;
        const int d0 = (tid & 255) * 2;
        const float* __restrict__ xp =
            inp + ((long)blockIdx.x * 2 + gg) * (64 * 512) + d0;
        float ax = 0.f, ay = 0.f;
#pragma unroll 8
        for (int n = 0; n < 64; ++n) {
            const float an  = a_s[gg][n];
            const float2 xv = *reinterpret_cast<const float2*>(&xp[n * 512]);
            ax = fmaf(an, xv.x, ax);
            ay = fmaf(an, xv.y, ay);
        }
        if (MODE == 0) {
            float2 o; o.x = ax; o.y = ay;
            *reinterpret_cast<float2*>(
                &dst[((long)blockIdx.x * 2 + gg) * 512 + d0]) = o;
        } else {
            attr_s[gg][d0]     = ax;
            attr_s[gg][d0 + 1] = ay;
        }
    }

    if (MODE == 1) {
        __syncthreads();
        // fused fc fallback: thread = (gg, o)
        const int gg = tid >> 8;
        const int o  = tid & 255;
        const float* __restrict__ wr = fc1_w + o * 512;
        const float* __restrict__ ap = attr_s[gg];
        float s0 = 0.f, s1 = 0.f, s2 = 0.f, s3 = 0.f;
#pragma unroll 8
        for (int i = 0; i < 128; ++i) {
            const float4 w4 = *reinterpret_cast<const float4*>(&wr[i * 4]);
            const float4 a4 = *reinterpret_cast<const float4*>(&ap[i * 4]);
            s0 = fmaf(a4.x, w4.x, s0);
            s1 = fmaf(a4.y, w4.y, s1);
            s2 = fmaf(a4.z, w4.z, s2);
            s3 = fmaf(a4.w, w4.w, s3);
        }
        const long btg = (long)blockIdx.x * 2 + gg;
        const int row  = (int)(btg & 31) * 32 + (int)(btg >> 5);
        dst[row * 256 + o] = (s0 + s1) + (s2 + s3) + fc1_b[o];
    }
}

// fc GEMM: out[(bt&31)*32+(bt>>5)][o] = attr[bt] . fc1_w[o] + fc1_b[o]
__global__ __launch_bounds__(256, 2) void stattn_fc2(
    const float* __restrict__ attr,   // [1024][512] (d_ws)
    const float* __restrict__ fc1_w,  // [256][512]
    const float* __restrict__ fc1_b,  // [256]
    float* __restrict__ out)          // [1024][256]
{
    __shared__ __align__(16) float at[32][516];
    const int tid = threadIdx.x;
    const int bm  = blockIdx.x;   // bt tile
    const int bn  = blockIdx.y;   // o tile

    {   // stage attr tile 32x512
        const int row = tid >> 3;
        const int seg = tid & 7;
        const float* __restrict__ src = attr + (size_t)(bm * 32 + row) * 512 + seg * 64;
#pragma unroll
        for (int q = 0; q < 16; ++q)
            *reinterpret_cast<float4*>(&at[row][seg * 64 + q * 4]) =
                *reinterpret_cast<const float4*>(&src[q * 4]);
    }
    __syncthreads();

    const int tx = tid & 31;   // o within tile
    const int ty = tid >> 5;   // bt quad
    const int o  = bn * 32 + tx;
    const float* __restrict__ wr = fc1_w + (size_t)o * 512;
    float s0 = 0.f, s1 = 0.f, s2 = 0.f, s3 = 0.f;
#pragma unroll 4
    for (int kq = 0; kq < 128; ++kq) {
        const float4 w4 = *reinterpret_cast<const float4*>(&wr[kq * 4]);
        const float4 a0 = *reinterpret_cast<const float4*>(&at[ty * 4 + 0][kq * 4]);
        const float4 a1 = *reinterpret_cast<const float4*>(&at[ty * 4 + 1][kq * 4]);
        const float4 a2 = *reinterpret_cast<const float4*>(&at[ty * 4 + 2][kq * 4]);
        const float4 a3 = *reinterpret_cast<const float4*>(&at[ty * 4 + 3][kq * 4]);
        s0 += a0.x * w4.x + a0.y * w4.y + a0.z * w4.z + a0.w * w4.w;
        s1 += a1.x * w4.x + a1.y * w4.y + a1.z * w4.z + a1.w * w4.w;
        s2 += a2.x * w4.x + a2.y * w4.y + a2.z * w4.z + a2.w * w4.w;
        s3 += a3.x * w4.x + a3.y * w4.y + a3.z * w4.z + a3.w * w4.w;
    }
    const float fb = fc1_b[o];
    float sv[4] = {s0, s1, s2, s3};
#pragma unroll
    for (int j = 0; j < 4; ++j) {
        const int bt  = bm * 32 + ty * 4 + j;
        const int row = (bt & 31) * 32 + (bt >> 5);
        out[row * 256 + o] = sv[j] + fb;
    }
}

extern "C" void kernel_launch(void* const* d_in, const int* in_sizes, int n_in,
                              void* d_out, int out_size, void* d_ws, size_t ws_size,
                              hipStream_t stream) {
    const float* inp   = (const float*)d_in[0];
    const float* ue_w  = (const float*)d_in[1];
    const float* ue_b  = (const float*)d_in[2];
    const float* be    = (const float*)d_in[3];
    const float* w_w   = (const float*)d_in[4];
    // d_in[5] = w_b: unused (softmax invariant to constant shift)
    const float* fc1_w = (const float*)d_in[6];
    const float* fc1_b = (const float*)d_in[7];
    float* out = (float*)d_out;

    const bool split = ws_size >= (size_t)1024 * 512 * 4;  // 2MB for attr
    if (split) {
        float* attr = (float*)d_ws;
        stattn_main<0><<<512, 512, 0, stream>>>(inp, ue_w, ue_b, be, w_w,
                                                fc1_w, fc1_b, attr);
        stattn_fc2<<<dim3(32, 8), 256, 0, stream>>>(attr, fc1_w, fc1_b, out);
    } else {
        stattn_main<1><<<512, 512, 0, stream>>>(inp, ue_w, ue_b, be, w_w,
                                                fc1_w, fc1_b, out);
    }
}

// Round 8
// 79.356 us; speedup vs baseline: 1.2293x; 1.2293x over previous
//
#include <hip/hip_runtime.h>

// STAttn v7: B,T,N,D=32,32,64,512; H=64; OUT=256.
// Kernel A: 1024 blocks (1 bt) x 512 thr (8 waves = (nh,jh,kh)).
//   x staged tile-by-tile (8 tiles of 64 cols x 64 rows, 16KB) into a 3-slot
//   LDS ring via global_load_lds(16B), swizzled (chunk^row&7) source-side.
//   T3/T4: depth-2 prefetch, counted s_waitcnt vmcnt(2) (never 0 in loop),
//   ONE s_barrier per tile, sched_barrier-pinned issue order:
//     per-wave FIFO: B0 S0 S1 | [w2] B1 S2 | [w2] B2 S3 | ... | [w0] at t=7.
//   ue_w fragments register-prefetched 1 tile ahead (B_t), split at use.
//   bf16 hi/lo trunc-split, 3x mfma_f32_32x32x16_bf16 per 16-k step.
// Then: kh-combine (ring reused as scratch), e=lrelu(h+b)@w_w, softmax,
//   pooling from global (L3-warm), attr -> d_ws; fc2 kernel does the fc GEMM.
// MODE 1 fallback (small ws): fc fused in-block.

typedef __attribute__((ext_vector_type(8)))  short bf16x8;
typedef __attribute__((ext_vector_type(16))) float f32x16;

#define AS3(p) ((__attribute__((address_space(3))) void*)(p))
#define AS1(p) ((const __attribute__((address_space(1))) void*)(p))
#define SCHEDB() __builtin_amdgcn_sched_barrier(0)

// fp32 -> bf16 hi (trunc) + lo (residual, trunc); alo*blo (~2^-16) dropped.
__device__ __forceinline__ void split8t(const float* __restrict__ v,
                                        bf16x8& h8, bf16x8& l8) {
#pragma unroll
    for (int i = 0; i < 8; ++i) {
        const unsigned u = __float_as_uint(v[i]);
        h8[i] = (short)(u >> 16);
        const float hf = __uint_as_float(u & 0xFFFF0000u);
        l8[i] = (short)(__float_as_uint(v[i] - hf) >> 16);
    }
}

template<int MODE>
__global__ __launch_bounds__(512, 2) void stattn_main(
    const float* __restrict__ inp,    // [1024][64][512]
    const float* __restrict__ ue_w,   // [64][512]
    const float* __restrict__ ue_b,   // [64]
    const float* __restrict__ be,     // [64]
    const float* __restrict__ w_w,    // [64]
    const float* __restrict__ fc1_w,  // [256][512] (MODE 1 only)
    const float* __restrict__ fc1_b,  // [256]      (MODE 1 only)
    float* __restrict__ dst)          // MODE 0: attr[1024][512]; MODE 1: out
{
    __shared__ __align__(16) float ring[3][64][64];  // 48 KB, 3-slot tile ring
    __shared__ float ep_s[2][64];
    __shared__ float a_s[64];
    __shared__ __align__(16) float attr_s[512];      // MODE 1 only

    const int tid = threadIdx.x;
    const int wv  = tid >> 6;
    const int l   = tid & 63;
    const int l31 = l & 31;
    const int hi5 = l >> 5;
    const int kh  = wv & 1;         // 32-col half within each 64-col tile
    const int jh  = (wv >> 1) & 1;  // hidden half
    const int nh  = wv >> 2;        // token half
    const float* __restrict__ xg = inp + (size_t)blockIdx.x * (64 * 512);

    // staging source (swizzled): wave stages rows [wv*8, wv*8+8), 2 instrs.
    // dest lane L -> row_local = L>>4, u16 = L&15; physical chunk u16>>1 holds
    // logical chunk (u16>>1)^(row&7)  (XOR self-inverse; read undoes it).
    const int r_a  = wv * 8 + (l >> 4);
    const int r_b  = r_a + 4;
    const int cph  = (l & 15) >> 1;
    const int hfl  = l & 1;
    const int colA = (cph ^ (r_a & 7)) * 8 + hfl * 4;
    const int colB = (cph ^ (r_b & 7)) * 8 + hfl * 4;
    const float* __restrict__ gxa = xg + r_a * 512 + colA;
    const float* __restrict__ gxb = xg + r_b * 512 + colB;

#define STAGE(t_) do {                                                        \
    __builtin_amdgcn_global_load_lds(AS1(gxa + (t_) * 64),                    \
        AS3((char*)&ring[(t_) % 3][wv * 8][0]), 16, 0, 0);                    \
    __builtin_amdgcn_global_load_lds(AS1(gxb + (t_) * 64),                    \
        AS3((char*)&ring[(t_) % 3][wv * 8 + 4][0]), 16, 0, 0);                \
} while (0)

    const int arow = nh * 32 + l31;                    // x row in tile
    const float* __restrict__ brow = ue_w + (jh * 32 + l31) * 512;
    const int bc0 = (kh * 4 + 0 + hi5) * 8;            // s=0 logical col off
    const int bc1 = (kh * 4 + 2 + hi5) * 8;            // s=1 logical col off
    const int pa0 = ((kh * 4 + 0 + hi5) ^ (arow & 7)) * 8;  // swizzled LDS
    const int pa1 = ((kh * 4 + 2 + hi5) ^ (arow & 7)) * 8;

    f32x16 acc = {};
    float4 bA0, bA1, bA2, bA3;   // current tile's ue_w frags (2 ksteps)

    // ---- prologue: B0 then S0, S1 (FIFO order pinned) ----
    bA0 = *reinterpret_cast<const float4*>(&brow[bc0]);
    bA1 = *reinterpret_cast<const float4*>(&brow[bc0 + 4]);
    bA2 = *reinterpret_cast<const float4*>(&brow[bc1]);
    bA3 = *reinterpret_cast<const float4*>(&brow[bc1 + 4]);
    SCHEDB();
    STAGE(0);
    STAGE(1);
    SCHEDB();

#pragma unroll
    for (int t = 0; t < 8; ++t) {
        if (t < 7) asm volatile("s_waitcnt vmcnt(2)" ::: "memory");
        else       asm volatile("s_waitcnt vmcnt(0)" ::: "memory");
        SCHEDB();
        __builtin_amdgcn_s_barrier();
        SCHEDB();
        // issue B_{t+1} (older than S_{t+2} in FIFO)
        float4 bn0, bn1, bn2, bn3;
        if (t < 7) {
            const float* __restrict__ bp = brow + (t + 1) * 64;
            bn0 = *reinterpret_cast<const float4*>(&bp[bc0]);
            bn1 = *reinterpret_cast<const float4*>(&bp[bc0 + 4]);
            bn2 = *reinterpret_cast<const float4*>(&bp[bc1]);
            bn3 = *reinterpret_cast<const float4*>(&bp[bc1 + 4]);
        }
        SCHEDB();
        if (t < 6) STAGE(t + 2);
        SCHEDB();
        // compute tile t from ring slot t%3 + bA regs
        {
            const float* __restrict__ rrow = &ring[t % 3][arow][0];
            float av[8], bv[8];
            bf16x8 ah, al, bh, bl;
            // kstep s=0
            *reinterpret_cast<float4*>(&av[0]) = *reinterpret_cast<const float4*>(&rrow[pa0]);
            *reinterpret_cast<float4*>(&av[4]) = *reinterpret_cast<const float4*>(&rrow[pa0 + 4]);
            *reinterpret_cast<float4*>(&bv[0]) = bA0;
            *reinterpret_cast<float4*>(&bv[4]) = bA1;
            split8t(av, ah, al);
            split8t(bv, bh, bl);
            acc = __builtin_amdgcn_mfma_f32_32x32x16_bf16(ah, bh, acc, 0, 0, 0);
            acc = __builtin_amdgcn_mfma_f32_32x32x16_bf16(al, bh, acc, 0, 0, 0);
            acc = __builtin_amdgcn_mfma_f32_32x32x16_bf16(ah, bl, acc, 0, 0, 0);
            // kstep s=1
            *reinterpret_cast<float4*>(&av[0]) = *reinterpret_cast<const float4*>(&rrow[pa1]);
            *reinterpret_cast<float4*>(&av[4]) = *reinterpret_cast<const float4*>(&rrow[pa1 + 4]);
            *reinterpret_cast<float4*>(&bv[0]) = bA2;
            *reinterpret_cast<float4*>(&bv[4]) = bA3;
            split8t(av, ah, al);
            split8t(bv, bh, bl);
            acc = __builtin_amdgcn_mfma_f32_32x32x16_bf16(ah, bh, acc, 0, 0, 0);
            acc = __builtin_amdgcn_mfma_f32_32x32x16_bf16(al, bh, acc, 0, 0, 0);
            acc = __builtin_amdgcn_mfma_f32_32x32x16_bf16(ah, bl, acc, 0, 0, 0);
        }
        bA0 = bn0; bA1 = bn1; bA2 = bn2; bA3 = bn3;
    }

    // ---- kh-combine (ring reused as fp32 scratch: 4 tiles x 1024) ----
    __syncthreads();
    {
        float* hp = &ring[0][0][0];
        const int toff = (nh * 2 + jh) * 1024 + l;
        if (kh == 1) {
#pragma unroll
            for (int r = 0; r < 16; ++r) hp[toff + r * 64] = acc[r];
        }
        __syncthreads();
        if (kh == 0) {
#pragma unroll
            for (int r = 0; r < 16; ++r) acc[r] += hp[toff + r * 64];
            // phase 2: bias + lrelu + dot w_w (w_b dropped: softmax shift-inv)
            // C/D layout: col j = l&31, row n = (r&3) + 8*(r>>2) + 4*(l>>5)
            const int j = jh * 32 + l31;
            const float bias = ue_b[j] + be[j];
            const float ww   = w_w[j];
#pragma unroll
            for (int r = 0; r < 16; ++r) {
                float hv = acc[r] + bias;
                hv = hv > 0.f ? hv : 0.2f * hv;
                float p = hv * ww;
                p += __shfl_xor(p, 1);
                p += __shfl_xor(p, 2);
                p += __shfl_xor(p, 4);
                p += __shfl_xor(p, 8);
                p += __shfl_xor(p, 16);
                if (l31 == 0) {
                    const int nr = (r & 3) + 8 * (r >> 2) + 4 * hi5;
                    ep_s[jh][nh * 32 + nr] = p;
                }
            }
        }
    }
    __syncthreads();

    // ---- softmax over 64 tokens ----
    {
        const float v = ep_s[0][l] + ep_s[1][l];
        float mx = v;
#pragma unroll
        for (int off = 32; off >= 1; off >>= 1) mx = fmaxf(mx, __shfl_xor(mx, off));
        const float ex = expf(v - mx);
        float sm = ex;
#pragma unroll
        for (int off = 32; off >= 1; off >>= 1) sm += __shfl_xor(sm, off);
        if (wv == 0) a_s[l] = ex / sm;
    }
    __syncthreads();

    // ---- pooling: thread d = tid (x re-read from global, L2/L3-warm) ----
    {
        const int d = tid;
        float s = 0.f;
#pragma unroll 8
        for (int n = 0; n < 64; ++n) s = fmaf(a_s[n], xg[n * 512 + d], s);
        if (MODE == 0) {
            dst[(size_t)blockIdx.x * 512 + d] = s;
        } else {
            attr_s[d] = s;
        }
    }

    if (MODE == 1) {
        __syncthreads();
        const int o  = tid >> 1;
        const int ks = tid & 1;
        const float* __restrict__ wr = fc1_w + o * 512 + ks * 256;
        const float* __restrict__ ap = attr_s + ks * 256;
        float s0 = 0.f, s1 = 0.f, s2 = 0.f, s3 = 0.f;
#pragma unroll 8
        for (int i = 0; i < 64; ++i) {
            const float4 w4 = *reinterpret_cast<const float4*>(&wr[i * 4]);
            const float4 a4 = *reinterpret_cast<const float4*>(&ap[i * 4]);
            s0 = fmaf(a4.x, w4.x, s0);
            s1 = fmaf(a4.y, w4.y, s1);
            s2 = fmaf(a4.z, w4.z, s2);
            s3 = fmaf(a4.w, w4.w, s3);
        }
        float p = (s0 + s1) + (s2 + s3);
        p += __shfl_xor(p, 1);
        if (ks == 0) {
            const int bt  = blockIdx.x;
            const int row = (bt & 31) * 32 + (bt >> 5);
            dst[row * 256 + o] = p + fc1_b[o];
        }
    }
#undef STAGE
}

// fc GEMM: out[(bt&31)*32+(bt>>5)][o] = attr[bt] . fc1_w[o] + fc1_b[o]
__global__ __launch_bounds__(256, 2) void stattn_fc2(
    const float* __restrict__ attr,   // [1024][512] (d_ws)
    const float* __restrict__ fc1_w,  // [256][512]
    const float* __restrict__ fc1_b,  // [256]
    float* __restrict__ out)          // [1024][256]
{
    __shared__ __align__(16) float at[32][516];
    const int tid = threadIdx.x;
    const int bm  = blockIdx.x;
    const int bn  = blockIdx.y;

    {
        const int row = tid >> 3;
        const int seg = tid & 7;
        const float* __restrict__ src = attr + (size_t)(bm * 32 + row) * 512 + seg * 64;
#pragma unroll
        for (int q = 0; q < 16; ++q)
            *reinterpret_cast<float4*>(&at[row][seg * 64 + q * 4]) =
                *reinterpret_cast<const float4*>(&src[q * 4]);
    }
    __syncthreads();

    const int tx = tid & 31;
    const int ty = tid >> 5;
    const int o  = bn * 32 + tx;
    const float* __restrict__ wr = fc1_w + (size_t)o * 512;
    float s0 = 0.f, s1 = 0.f, s2 = 0.f, s3 = 0.f;
#pragma unroll 4
    for (int kq = 0; kq < 128; ++kq) {
        const float4 w4 = *reinterpret_cast<const float4*>(&wr[kq * 4]);
        const float4 a0 = *reinterpret_cast<const float4*>(&at[ty * 4 + 0][kq * 4]);
        const float4 a1 = *reinterpret_cast<const float4*>(&at[ty * 4 + 1][kq * 4]);
        const float4 a2 = *reinterpret_cast<const float4*>(&at[ty * 4 + 2][kq * 4]);
        const float4 a3 = *reinterpret_cast<const float4*>(&at[ty * 4 + 3][kq * 4]);
        s0 += a0.x * w4.x + a0.y * w4.y + a0.z * w4.z + a0.w * w4.w;
        s1 += a1.x * w4.x + a1.y * w4.y + a1.z * w4.z + a1.w * w4.w;
        s2 += a2.x * w4.x + a2.y * w4.y + a2.z * w4.z + a2.w * w4.w;
        s3 += a3.x * w4.x + a3.y * w4.y + a3.z * w4.z + a3.w * w4.w;
    }
    const float fb = fc1_b[o];
    float sv[4] = {s0, s1, s2, s3};
#pragma unroll
    for (int j = 0; j < 4; ++j) {
        const int bt  = bm * 32 + ty * 4 + j;
        const int row = (bt & 31) * 32 + (bt >> 5);
        out[row * 256 + o] = sv[j] + fb;
    }
}

extern "C" void kernel_launch(void* const* d_in, const int* in_sizes, int n_in,
                              void* d_out, int out_size, void* d_ws, size_t ws_size,
                              hipStream_t stream) {
    const float* inp   = (const float*)d_in[0];
    const float* ue_w  = (const float*)d_in[1];
    const float* ue_b  = (const float*)d_in[2];
    const float* be    = (const float*)d_in[3];
    const float* w_w   = (const float*)d_in[4];
    // d_in[5] = w_b: unused (softmax invariant to constant shift)
    const float* fc1_w = (const float*)d_in[6];
    const float* fc1_b = (const float*)d_in[7];
    float* out = (float*)d_out;

    const bool split = ws_size >= (size_t)1024 * 512 * 4;  // 2MB (confirmed R6)
    if (split) {
        float* attr = (float*)d_ws;
        stattn_main<0><<<1024, 512, 0, stream>>>(inp, ue_w, ue_b, be, w_w,
                                                 fc1_w, fc1_b, attr);
        stattn_fc2<<<dim3(32, 8), 256, 0, stream>>>(attr, fc1_w, fc1_b, out);
    } else {
        stattn_main<1><<<1024, 512, 0, stream>>>(inp, ue_w, ue_b, be, w_w,
                                                 fc1_w, fc1_b, out);
    }
}